// Round 4
// baseline (171.892 us; speedup 1.0000x reference)
//
#include <hip/hip_runtime.h>

#define MAX_RIGID 8

// XOR bank swizzle: bijective involution within any 32-dword-aligned block
__device__ __forceinline__ int swz(int a) { return a ^ ((a >> 5) & 31); }

__device__ __forceinline__ void load12(const float* __restrict__ base, float* X) {
    const float4* p = reinterpret_cast<const float4*>(base);
    float4 a = p[0], b = p[1], c = p[2];
    X[0]=a.x; X[1]=a.y; X[2]=a.z;  X[3]=a.w;
    X[4]=b.x; X[5]=b.y; X[6]=b.z;  X[7]=b.w;
    X[8]=c.x; X[9]=c.y; X[10]=c.z; X[11]=c.w;
}

// X,Y,O are 4x3 affine: [0..8] rot row-major, [9..11] translation
__device__ __forceinline__ void combine12(const float* X, const float* Y, float* O) {
    #pragma unroll
    for (int i = 0; i < 3; ++i) {
        #pragma unroll
        for (int k = 0; k < 3; ++k)
            O[i*3+k] = X[i*3+0]*Y[0+k] + X[i*3+1]*Y[3+k] + X[i*3+2]*Y[6+k];
        O[9+i] = X[i*3+0]*Y[9] + X[i*3+1]*Y[10] + X[i*3+2]*Y[11] + X[9+i];
    }
}

__device__ __forceinline__ void compute_node(
    const float* o0r, const float* o1r, float px, float py, float pz,
    float tscale, const float* __restrict__ Tbase, const int* __restrict__ td,
    float sc[14], float bb[12], float opr[MAX_RIGID][12])
{
    #pragma unroll
    for (int k = 0; k < 7; ++k) {
        float a = o0r[2*k], b = o0r[2*k+1];
        float r = 1.0f / sqrtf(a*a + b*b + 1e-12f);
        sc[2*k] = a*r; sc[2*k+1] = b*r;
    }
    float v0x=o1r[0], v0y=o1r[1], v0z=o1r[2];
    float v1x=o1r[3], v1y=o1r[4], v1z=o1r[5];
    float r0 = 1.0f / sqrtf(v0x*v0x + v0y*v0y + v0z*v0z + 1e-12f);
    float e0x=v0x*r0, e0y=v0y*r0, e0z=v0z*r0;
    float dp = e0x*v1x + e0y*v1y + e0z*v1z;
    float u1x = v1x - e0x*dp, u1y = v1y - e0y*dp, u1z = v1z - e0z*dp;
    float r1 = 1.0f / sqrtf(u1x*u1x + u1y*u1y + u1z*u1z + 1e-12f);
    float e1x=u1x*r1, e1y=u1y*r1, e1z=u1z*r1;
    float e2x = e0y*e1z - e0z*e1y;
    float e2y = e0z*e1x - e0x*e1z;
    float e2z = e0x*e1y - e0y*e1x;
    float tx = tscale*o1r[6], ty = tscale*o1r[7], tz = tscale*o1r[8];
    bb[0]=e0x; bb[1]=e1x; bb[2]=e2x;
    bb[3]=e0y; bb[4]=e1y; bb[5]=e2y;
    bb[6]=e0z; bb[7]=e1z; bb[8]=e2z;
    bb[9]=tx;  bb[10]=ty; bb[11]=tz;

    {
        float X[12]; load12(Tbase, X);
        float Y[12] = { bb[0],bb[1],bb[2], bb[3],bb[4],bb[5], bb[6],bb[7],bb[8],
                        tx+px, ty+py, tz+pz };
        combine12(X, Y, opr[0]);
    }
    #pragma unroll
    for (int i = 1; i < MAX_RIGID; ++i) {
        float X[12]; load12(Tbase + i*12, X);
        float c = sc[2*(i-1)], s = sc[2*(i-1)+1];
        float M[12];
        M[0]=X[0]; M[3]=X[3]; M[6]=X[6];
        M[1] = c*X[1] + s*X[2];   M[2] = c*X[2] - s*X[1];
        M[4] = c*X[4] + s*X[5];   M[5] = c*X[5] - s*X[4];
        M[7] = c*X[7] + s*X[8];   M[8] = c*X[8] - s*X[7];
        M[9]=X[9]; M[10]=X[10]; M[11]=X[11];
        int t = td[i];
        float P[12];
        #pragma unroll
        for (int j = 0; j < 12; ++j) P[j] = opr[0][j];
        #pragma unroll
        for (int cnd = 1; cnd < i; ++cnd) {
            bool take = (t == cnd);
            #pragma unroll
            for (int j = 0; j < 12; ++j) P[j] = take ? opr[cnd][j] : P[j];
        }
        combine12(P, M, opr[i]);
    }
}

__device__ __forceinline__ void atom_xyz(const float opr[MAX_RIGID][12], int g,
                                         float gx, float gy, float gz,
                                         float& x, float& y, float& z)
{
    float O[12];
    #pragma unroll
    for (int j = 0; j < 12; ++j) O[j] = opr[0][j];
    #pragma unroll
    for (int cnd = 1; cnd < MAX_RIGID; ++cnd) {
        bool take = (g == cnd);
        #pragma unroll
        for (int j = 0; j < 12; ++j) O[j] = take ? opr[cnd][j] : O[j];
    }
    x = O[0]*gx + O[1]*gy + O[2]*gz + O[9];
    y = O[3]*gx + O[4]*gy + O[5]*gz + O[10];
    z = O[6]*gx + O[7]*gy + O[8]*gz + O[11];
}

// LDS per wave (dwords): stage-in o0[0,896) o1[896,1472) pos[1472,1664)
//                        small-out sc[0,896) bb[896,1664) opr0[1664,2432)
//                        R chunks  [0,1536)
__global__ __launch_bounds__(256) void build_struct_kernel(
    const float* __restrict__ out0,   // [N,14]
    const float* __restrict__ out1,   // [N,9]
    const float* __restrict__ pos,    // [N,3]
    const float* __restrict__ rigidT, // [22,8,12]
    const float* __restrict__ rigidG, // [22,24,3]
    const int*   __restrict__ resty,  // [N]
    const int*   __restrict__ tdep,   // [22,8]
    const int*   __restrict__ gdep,   // [22,24]
    const int*   __restrict__ nrp,
    float* __restrict__ dR,           // [N,72]
    float* __restrict__ dOprBB,       // [N,12]
    float* __restrict__ dBB,          // [N,12]
    float* __restrict__ dSC,          // [N,14]
    int N)
{
    __shared__ float smem[4 * 2432];   // 38912 B per block
    const int lane = threadIdx.x & 63;
    const int w    = threadIdx.x >> 6;
    const long node0 = (long)blockIdx.x * 256 + (long)w * 64;
    float* buf = smem + w * 2432;

    // valid node count for this wave (0..64); all waves run the full barrier skeleton
    int cnt;
    {
        long rem = (long)N - node0;
        cnt = (rem <= 0) ? 0 : (rem >= 64 ? 64 : (int)rem);
    }

    int iv = *nrp;
    float nrv = (iv > 0 && iv < 1000000) ? (float)iv
                                         : *reinterpret_cast<const float*>(nrp);
    float tscale = 0.1f / nrv;

    // ---- stage-in: dense global reads -> LDS (guarded for partial waves)
    {
        const float* g0 = out0 + node0 * 14;
        #pragma unroll
        for (int j = 0; j < 14; ++j) { int e = j*64 + lane; if (e < cnt*14) buf[swz(e)] = g0[e]; }
        const float* g1 = out1 + node0 * 9;
        #pragma unroll
        for (int j = 0; j < 9; ++j)  { int e = j*64 + lane; if (e < cnt*9)  buf[896 + e] = g1[e]; }
        const float* gp = pos + node0 * 3;
        #pragma unroll
        for (int j = 0; j < 3; ++j)  { int e = j*64 + lane; if (e < cnt*3)  buf[1472 + e] = gp[e]; }
    }
    __syncthreads();

    // ---- per-lane reads from LDS (invalid lanes read stale data; results unused)
    float o0r[14], o1r[9];
    #pragma unroll
    for (int k = 0; k < 14; ++k) o0r[k] = buf[swz(lane*14 + k)];
    #pragma unroll
    for (int k = 0; k < 9; ++k)  o1r[k] = buf[896 + lane*9 + k];
    float px = buf[1472 + lane*3 + 0];
    float py = buf[1472 + lane*3 + 1];
    float pz = buf[1472 + lane*3 + 2];

    int n = (int)node0 + lane;
    if (n >= N) n = N - 1;                 // clamp for safe table reads
    int rt = resty[n];
    const float* Tbase = rigidT + rt * 96;
    const int*   td    = tdep   + rt * 8;

    float sc[14], bb[12], opr[MAX_RIGID][12];
    compute_node(o0r, o1r, px, py, pz, tscale, Tbase, td, sc, bb, opr);

    __syncthreads();   // WAR: staging regions consumed, about to overwrite

    // ---- stage-out small outputs
    #pragma unroll
    for (int k = 0; k < 14; ++k) buf[swz(lane*14 + k)] = sc[k];
    #pragma unroll
    for (int k = 0; k < 12; ++k) buf[swz(896 + lane*12 + k)] = bb[k];
    #pragma unroll
    for (int k = 0; k < 12; ++k) buf[swz(1664 + lane*12 + k)] = opr[0][k];
    __syncthreads();
    {
        float* d0 = dSC + node0 * 14;
        #pragma unroll
        for (int j = 0; j < 14; ++j) { int e = j*64 + lane; if (e < cnt*14) d0[e] = buf[swz(e)]; }
        float* d1 = dBB + node0 * 12;
        #pragma unroll
        for (int j = 0; j < 12; ++j) { int e = j*64 + lane; if (e < cnt*12) d1[e] = buf[swz(896 + e)]; }
        float* d2 = dOprBB + node0 * 12;
        #pragma unroll
        for (int j = 0; j < 12; ++j) { int e = j*64 + lane; if (e < cnt*12) d2[e] = buf[swz(1664 + e)]; }
    }
    __syncthreads();   // WAR: small-out regions consumed, R chunks will overwrite

    // ---- R in 3 chunks of 8 atoms (24 dwords per node per chunk)
    // e = j*64+lane; with r=(j*64)%24 in {0,16,8}: e/24 = (j*64)/24 + (lane+r)/24,
    // e%24 = (lane+r)%24.  lane+r <= 79 so the quotient can be 0..3 (R3 bug: capped at 2).
    int offr[3];
    {
        const int rs[3] = {0, 16, 8};
        #pragma unroll
        for (int t = 0; t < 3; ++t) {
            int lr = lane + rs[t];
            int d  = lr / 24;                 // 0..3
            offr[t] = d * 72 + (lr - d * 24);
        }
    }
    const int*   gd = gdep   + rt * 24;
    const float* Gb = rigidG + rt * 72;
    #pragma unroll
    for (int c = 0; c < 3; ++c) {
        #pragma unroll
        for (int a4 = 0; a4 < 8; ++a4) {
            int a = c*8 + a4;
            int g = gd[a];
            float x, y, z;
            atom_xyz(opr, g, Gb[a*3+0], Gb[a*3+1], Gb[a*3+2], x, y, z);
            buf[swz(lane*24 + a4*3 + 0)] = x;
            buf[swz(lane*24 + a4*3 + 1)] = y;
            buf[swz(lane*24 + a4*3 + 2)] = z;
        }
        __syncthreads();
        float* rdst = dR + node0 * 72 + c * 24;
        #pragma unroll
        for (int j = 0; j < 24; ++j) {
            int e = j*64 + lane;
            if (e < cnt*24) {
                float v = buf[swz(e)];
                rdst[((j*64)/24)*72 + offr[j % 3]] = v;   // == (e/24)*72 + e%24
            }
        }
        if (c < 2) __syncthreads();   // WAR before next chunk's writes
    }
}

extern "C" void kernel_launch(void* const* d_in, const int* in_sizes, int n_in,
                              void* d_out, int out_size, void* d_ws, size_t ws_size,
                              hipStream_t stream) {
    const float* out0 = (const float*)d_in[0];
    const float* out1 = (const float*)d_in[1];
    const float* pos  = (const float*)d_in[2];
    const float* rT   = (const float*)d_in[3];
    const float* rG   = (const float*)d_in[4];
    const int*   res  = (const int*)d_in[5];
    const int*   td   = (const int*)d_in[6];
    const int*   gd   = (const int*)d_in[7];
    const int*   nr   = (const int*)d_in[8];

    int N = in_sizes[5];

    float* dR     = (float*)d_out;
    float* dOprBB = dR + (size_t)N * 72;
    float* dBB    = dOprBB + (size_t)N * 12;
    float* dSC    = dBB + (size_t)N * 12;

    dim3 grid((N + 255) / 256), block(256);
    hipLaunchKernelGGL(build_struct_kernel, grid, block, 0, stream,
                       out0, out1, pos, rT, rG, res, td, gd, nr,
                       dR, dOprBB, dBB, dSC, N);
}

// Round 5
// 104.220 us; speedup vs baseline: 1.6493x; 1.6493x over previous
//
#include <hip/hip_runtime.h>

#define MAX_RIGID 8

// X,Y,O are 4x3 affine: [0..8] rot row-major, [9..11] translation
__device__ __forceinline__ void combine12(const float* X, const float* Y, float* O) {
    #pragma unroll
    for (int i = 0; i < 3; ++i) {
        #pragma unroll
        for (int k = 0; k < 3; ++k)
            O[i*3+k] = X[i*3+0]*Y[0+k] + X[i*3+1]*Y[3+k] + X[i*3+2]*Y[6+k];
        O[9+i] = X[i*3+0]*Y[9] + X[i*3+1]*Y[10] + X[i*3+2]*Y[11] + X[9+i];
    }
}

__device__ __forceinline__ void atom_xyz(const float opr[MAX_RIGID][12], int g,
                                         float gx, float gy, float gz,
                                         float& x, float& y, float& z)
{
    float O[12];
    #pragma unroll
    for (int j = 0; j < 12; ++j) O[j] = opr[0][j];
    #pragma unroll
    for (int cnd = 1; cnd < MAX_RIGID; ++cnd) {
        bool take = (g == cnd);
        #pragma unroll
        for (int j = 0; j < 12; ++j) O[j] = take ? opr[cnd][j] : O[j];
    }
    x = O[0]*gx + O[1]*gy + O[2]*gz + O[9];
    y = O[3]*gx + O[4]*gy + O[5]*gz + O[10];
    z = O[6]*gx + O[7]*gy + O[8]*gz + O[11];
}

__global__ __launch_bounds__(256) void build_struct_kernel(
    const float* __restrict__ out0,   // [N,14]
    const float* __restrict__ out1,   // [N,9]
    const float* __restrict__ pos,    // [N,3]
    const float* __restrict__ rigidT, // [22,8,12]
    const float* __restrict__ rigidG, // [22,24,3]
    const int*   __restrict__ resty,  // [N]
    const int*   __restrict__ tdep,   // [22,8]
    const int*   __restrict__ gdep,   // [22,24]
    const int*   __restrict__ nrp,
    float* __restrict__ dR,           // [N,72]
    float* __restrict__ dOprBB,       // [N,12]
    float* __restrict__ dBB,          // [N,12]
    float* __restrict__ dSC,          // [N,14]
    int N)
{
    __shared__ float sT[2112];        // [22][8][12]
    __shared__ float sG[2112];        // [22][24][4] (padded, .w unused)
    __shared__ int   sgd[528];        // [22][24]
    __shared__ int   stdp[176];       // [22][8]
    __shared__ float sbuf[4][1792];   // per-wave transpose buffer

    const int tid  = threadIdx.x;
    const int lane = tid & 63;
    const int w    = tid >> 6;
    const long node0 = (long)blockIdx.x * 256 + (long)w * 64;
    float* buf = sbuf[w];

    // ---- table staging (whole block, coalesced) ----
    for (int i = tid; i < 2112; i += 256) sT[i] = rigidT[i];
    for (int i = tid; i < 1584; i += 256) { int q = i / 3; sG[q*4 + (i - q*3)] = rigidG[i]; }
    for (int i = tid; i < 528;  i += 256) sgd[i]  = gdep[i];
    for (int i = tid; i < 176;  i += 256) stdp[i] = tdep[i];

    // valid node count for this wave; ALL waves run the full barrier skeleton
    int cnt;
    {
        long rem = (long)N - node0;
        cnt = (rem <= 0) ? 0 : (rem >= 64 ? 64 : (int)rem);
    }

    int iv = *nrp;
    float nrv = (iv > 0 && iv < 1000000) ? (float)iv
                                         : *reinterpret_cast<const float*>(nrp);
    float tscale = 0.1f / nrv;

    // ---- direct per-lane input loads (L1/L2-friendly, read-once) ----
    int n = (int)node0 + lane;
    if (n >= N) n = N - 1;            // clamp: results from clamped lanes never stored
    float o0r[14];
    {
        const float2* p = reinterpret_cast<const float2*>(out0 + (size_t)n * 14);
        #pragma unroll
        for (int k = 0; k < 7; ++k) { float2 v = p[k]; o0r[2*k] = v.x; o0r[2*k+1] = v.y; }
    }
    float o1r[9];
    {
        const float* p = out1 + (size_t)n * 9;
        #pragma unroll
        for (int k = 0; k < 9; ++k) o1r[k] = p[k];
    }
    float px = pos[(size_t)n*3+0], py = pos[(size_t)n*3+1], pz = pos[(size_t)n*3+2];
    int rt = resty[n];

    __syncthreads();   // tables ready

    // ---- math: sc, bb ----
    float sc[14];
    #pragma unroll
    for (int k = 0; k < 7; ++k) {
        float a = o0r[2*k], b = o0r[2*k+1];
        float r = 1.0f / sqrtf(a*a + b*b + 1e-12f);
        sc[2*k] = a*r; sc[2*k+1] = b*r;
    }
    float bb[12];
    {
        float v0x=o1r[0], v0y=o1r[1], v0z=o1r[2];
        float v1x=o1r[3], v1y=o1r[4], v1z=o1r[5];
        float r0 = 1.0f / sqrtf(v0x*v0x + v0y*v0y + v0z*v0z + 1e-12f);
        float e0x=v0x*r0, e0y=v0y*r0, e0z=v0z*r0;
        float dp = e0x*v1x + e0y*v1y + e0z*v1z;
        float u1x = v1x - e0x*dp, u1y = v1y - e0y*dp, u1z = v1z - e0z*dp;
        float r1 = 1.0f / sqrtf(u1x*u1x + u1y*u1y + u1z*u1z + 1e-12f);
        float e1x=u1x*r1, e1y=u1y*r1, e1z=u1z*r1;
        float e2x = e0y*e1z - e0z*e1y;
        float e2y = e0z*e1x - e0x*e1z;
        float e2z = e0x*e1y - e0y*e1x;
        bb[0]=e0x; bb[1]=e1x; bb[2]=e2x;
        bb[3]=e0y; bb[4]=e1y; bb[5]=e2y;
        bb[6]=e0z; bb[7]=e1z; bb[8]=e2z;
        bb[9]=tscale*o1r[6]; bb[10]=tscale*o1r[7]; bb[11]=tscale*o1r[8];
    }

    // ---- table gathers from LDS ----
    const float4* T4 = reinterpret_cast<const float4*>(sT + rt * 96);   // 16B-aligned
    int tdr[8];
    {
        const int4* t4 = reinterpret_cast<const int4*>(stdp + rt * 8);
        int4 a = t4[0], b = t4[1];
        tdr[0]=a.x; tdr[1]=a.y; tdr[2]=a.z; tdr[3]=a.w;
        tdr[4]=b.x; tdr[5]=b.y; tdr[6]=b.z; tdr[7]=b.w;
    }

    // ---- rigid chain ----
    float opr[MAX_RIGID][12];
    {
        float X[12];
        { float4 r0v=T4[0], r1v=T4[1], r2v=T4[2];
          X[0]=r0v.x; X[1]=r0v.y; X[2]=r0v.z; X[3]=r0v.w;
          X[4]=r1v.x; X[5]=r1v.y; X[6]=r1v.z; X[7]=r1v.w;
          X[8]=r2v.x; X[9]=r2v.y; X[10]=r2v.z; X[11]=r2v.w; }
        float Y[12] = { bb[0],bb[1],bb[2], bb[3],bb[4],bb[5], bb[6],bb[7],bb[8],
                        bb[9]+px, bb[10]+py, bb[11]+pz };
        combine12(X, Y, opr[0]);
    }
    #pragma unroll
    for (int i = 1; i < MAX_RIGID; ++i) {
        float X[12];
        { float4 r0v=T4[i*3], r1v=T4[i*3+1], r2v=T4[i*3+2];
          X[0]=r0v.x; X[1]=r0v.y; X[2]=r0v.z; X[3]=r0v.w;
          X[4]=r1v.x; X[5]=r1v.y; X[6]=r1v.z; X[7]=r1v.w;
          X[8]=r2v.x; X[9]=r2v.y; X[10]=r2v.z; X[11]=r2v.w; }
        float c = sc[2*(i-1)], s = sc[2*(i-1)+1];
        float M[12];
        M[0]=X[0]; M[3]=X[3]; M[6]=X[6];
        M[1] = c*X[1] + s*X[2];   M[2] = c*X[2] - s*X[1];
        M[4] = c*X[4] + s*X[5];   M[5] = c*X[5] - s*X[4];
        M[7] = c*X[7] + s*X[8];   M[8] = c*X[8] - s*X[7];
        M[9]=X[9]; M[10]=X[10]; M[11]=X[11];
        int t = tdr[i];
        float P[12];
        #pragma unroll
        for (int j = 0; j < 12; ++j) P[j] = opr[0][j];
        #pragma unroll
        for (int cnd = 1; cnd < i; ++cnd) {
            bool take = (t == cnd);
            #pragma unroll
            for (int j = 0; j < 12; ++j) P[j] = take ? opr[cnd][j] : P[j];
        }
        combine12(P, M, opr[i]);
    }

    // ========== phase SC: LDS stride 18, float2 readout ==========
    #pragma unroll
    for (int k = 0; k < 7; ++k)
        *reinterpret_cast<float2*>(&buf[lane*18 + 2*k]) = make_float2(sc[2*k], sc[2*k+1]);
    __syncthreads();
    {
        float* d0 = dSC + node0 * 14;
        #pragma unroll
        for (int j = 0; j < 7; ++j) {
            int e2 = j*128 + 2*lane;
            if (e2 < cnt*14) {
                int nd = e2 / 14; int m = e2 - nd*14;
                float2 v = *reinterpret_cast<const float2*>(&buf[nd*18 + m]);
                *reinterpret_cast<float2*>(&d0[e2]) = v;
            }
        }
    }
    __syncthreads();

    // ========== phase BB: LDS stride 20, float4 readout ==========
    #pragma unroll
    for (int k = 0; k < 3; ++k)
        *reinterpret_cast<float4*>(&buf[lane*20 + 4*k]) =
            make_float4(bb[4*k], bb[4*k+1], bb[4*k+2], bb[4*k+3]);
    __syncthreads();
    {
        float* d1 = dBB + node0 * 12;
        #pragma unroll
        for (int j = 0; j < 3; ++j) {
            int e = j*256 + 4*lane;
            if (e < cnt*12) {
                int nd = e / 12; int m = e - nd*12;     // m in {0,4,8}
                float4 v = *reinterpret_cast<const float4*>(&buf[nd*20 + m]);
                *reinterpret_cast<float4*>(&d1[e]) = v;
            }
        }
    }
    __syncthreads();

    // ========== phase OPR0: LDS stride 20, float4 readout ==========
    #pragma unroll
    for (int k = 0; k < 3; ++k)
        *reinterpret_cast<float4*>(&buf[lane*20 + 4*k]) =
            make_float4(opr[0][4*k], opr[0][4*k+1], opr[0][4*k+2], opr[0][4*k+3]);
    __syncthreads();
    {
        float* d2 = dOprBB + node0 * 12;
        #pragma unroll
        for (int j = 0; j < 3; ++j) {
            int e = j*256 + 4*lane;
            if (e < cnt*12) {
                int nd = e / 12; int m = e - nd*12;
                float4 v = *reinterpret_cast<const float4*>(&buf[nd*20 + m]);
                *reinterpret_cast<float4*>(&d2[e]) = v;
            }
        }
    }
    __syncthreads();

    // ========== R: 3 chunks x 8 atoms, LDS stride 28, float4 readout ==========
    const float4* G4  = reinterpret_cast<const float4*>(sG);
    const int4*   gd4 = reinterpret_cast<const int4*>(sgd + rt * 24);
    #pragma unroll
    for (int c = 0; c < 3; ++c) {
        int4 ga = gd4[c*2], gb = gd4[c*2+1];
        int gch[8] = {ga.x, ga.y, ga.z, ga.w, gb.x, gb.y, gb.z, gb.w};
        float rbuf[24];
        #pragma unroll
        for (int a4 = 0; a4 < 8; ++a4) {
            int a = c*8 + a4;
            float4 gv = G4[rt*24 + a];
            float x, y, z;
            atom_xyz(opr, gch[a4], gv.x, gv.y, gv.z, x, y, z);
            rbuf[a4*3+0] = x; rbuf[a4*3+1] = y; rbuf[a4*3+2] = z;
        }
        #pragma unroll
        for (int q = 0; q < 6; ++q)
            *reinterpret_cast<float4*>(&buf[lane*28 + 4*q]) =
                make_float4(rbuf[4*q], rbuf[4*q+1], rbuf[4*q+2], rbuf[4*q+3]);
        __syncthreads();
        {
            float* rdst = dR + node0 * 72 + c * 24;
            #pragma unroll
            for (int j = 0; j < 6; ++j) {
                int e = j*256 + 4*lane;
                if (e < cnt*24) {
                    int nd = e / 24; int m = e - nd*24;   // m in {0,4,...,20}
                    float4 v = *reinterpret_cast<const float4*>(&buf[nd*28 + m]);
                    *reinterpret_cast<float4*>(&rdst[nd*72 + m]) = v;
                }
            }
        }
        if (c < 2) __syncthreads();   // WAR before next chunk's writes
    }
}

extern "C" void kernel_launch(void* const* d_in, const int* in_sizes, int n_in,
                              void* d_out, int out_size, void* d_ws, size_t ws_size,
                              hipStream_t stream) {
    const float* out0 = (const float*)d_in[0];
    const float* out1 = (const float*)d_in[1];
    const float* pos  = (const float*)d_in[2];
    const float* rT   = (const float*)d_in[3];
    const float* rG   = (const float*)d_in[4];
    const int*   res  = (const int*)d_in[5];
    const int*   td   = (const int*)d_in[6];
    const int*   gd   = (const int*)d_in[7];
    const int*   nr   = (const int*)d_in[8];

    int N = in_sizes[5];

    float* dR     = (float*)d_out;
    float* dOprBB = dR + (size_t)N * 72;
    float* dBB    = dOprBB + (size_t)N * 12;
    float* dSC    = dBB + (size_t)N * 12;

    dim3 grid((N + 255) / 256), block(256);
    hipLaunchKernelGGL(build_struct_kernel, grid, block, 0, stream,
                       out0, out1, pos, rT, rG, res, td, gd, nr,
                       dR, dOprBB, dBB, dSC, N);
}